// Round 2
// baseline (70.158 us; speedup 1.0000x reference)
//
#include <hip/hip_runtime.h>
#include <math.h>

#define NB 8
#define NN 512
#define D 128
#define TI 4          // query rows per k2 block
#define K1R 8         // rows per k1 block
#define LN_EPS 1e-5f
#define SCALE 0.08838834764831845f  // 1/sqrt(128)

typedef float f32x4 __attribute__((ext_vector_type(4)));

__device__ __forceinline__ float dotv(f32x4 a, f32x4 b) {
    f32x4 m = a * b;
    return m.x + m.y + m.z + m.w;
}
__device__ __forceinline__ float dot4(float4 a, float4 b) {
    return a.x * b.x + a.y * b.y + a.z * b.z + a.w * b.w;
}

// ---------------- Kernel 1: h = x @ W^T, s_i, s_j ---------------------------
// grid: 512 blocks (8 rows each), block: 256. W staged in LDS (swizzled).
__global__ __launch_bounds__(256) void k1_proj(
    const float* __restrict__ x, const float* __restrict__ W,
    const float* __restrict__ a_src, const float* __restrict__ a_dst,
    float* __restrict__ h_ws, float* __restrict__ si_ws, float* __restrict__ sj_ws)
{
    __shared__ __align__(16) float4 Wl[128][32];   // [o][q ^ (o&7)] swizzle
    __shared__ __align__(16) float4 xl[K1R][32];
    __shared__ float redk[K1R][2][2];

    const int t = threadIdx.x;
    const int row0 = blockIdx.x * K1R;

    const float4* Wg = (const float4*)W;
#pragma unroll
    for (int k = 0; k < 16; ++k) {
        const int f = t + 256 * k;          // 4096 float4 of W
        const int o = f >> 5, q = f & 31;
        Wl[o][q ^ (o & 7)] = Wg[f];
    }
    xl[t >> 5][t & 31] = ((const float4*)(x + (size_t)row0 * D))[t];  // 256 float4
    __syncthreads();

    const int o = t & 127;
    const int rb = (t >> 7) * (K1R / 2);    // rows 0-3 or 4-7
    float acc[K1R / 2] = {0.f, 0.f, 0.f, 0.f};
#pragma unroll
    for (int q = 0; q < 32; ++q) {
        const float4 wv = Wl[o][q ^ (o & 7)];
#pragma unroll
        for (int r = 0; r < K1R / 2; ++r) acc[r] += dot4(wv, xl[rb + r][q]);
    }
    const float as = a_src[o], ad = a_dst[o];
#pragma unroll
    for (int r = 0; r < K1R / 2; ++r) {
        h_ws[(size_t)(row0 + rb + r) * D + o] = acc[r];
        float vs = acc[r] * as, vd = acc[r] * ad;
#pragma unroll
        for (int m = 32; m >= 1; m >>= 1) {
            vs += __shfl_xor(vs, m);
            vd += __shfl_xor(vd, m);
        }
        if ((t & 63) == 0) {
            redk[rb + r][0][(t >> 6) & 1] = vs;
            redk[rb + r][1][(t >> 6) & 1] = vd;
        }
    }
    __syncthreads();
    if (t < K1R) si_ws[row0 + t] = redk[t][0][0] + redk[t][0][1];
    else if (t < 2 * K1R) {
        const int r = t - K1R;
        sj_ws[row0 + r] = redk[r][1][0] + redk[r][1][1];
    }
}

// ---------------- Kernel 2: scores + softmax + PV + LayerNorm ---------------
// grid: 8 * 128 = 1024 blocks (TI=4 rows each), block: 256
__global__ __launch_bounds__(256) void k2_attn(
    const float* __restrict__ ef, const float* __restrict__ a_e,
    const float* __restrict__ gamma, const float* __restrict__ beta,
    const float* __restrict__ h_ws, const float* __restrict__ si_ws,
    const float* __restrict__ sj_ws, float* __restrict__ out)
{
    __shared__ float sj_l[NN];                        // 2 KB
    __shared__ __align__(16) float alpha_t[NN][TI];   // 8 KB, [j][r]
    __shared__ __align__(16) float part[4][TI][D];    // 8 KB
    __shared__ float redm[TI][4];
    __shared__ float reds[TI][4];

    const int t = threadIdx.x;
    const int w = t >> 6;
    const int lane = t & 63;
    const int bid = blockIdx.x;
    const int b = bid >> 7;            // 128 blocks per batch
    const int i0 = (bid & 127) << 2;   // first of TI=4 rows

    sj_l[t] = sj_ws[b * NN + t];
    sj_l[t + 256] = sj_ws[b * NN + t + 256];

    const f32x4* ae4 = (const f32x4*)a_e;
    const f32x4 A0 = ae4[0], A1 = ae4[1], A2 = ae4[2], A3 = ae4[3];
    __syncthreads();

    // Phase A: scores. thread owns j0 = t and j1 = t + 256 for each row.
    float e0[TI], e1[TI];
#pragma unroll
    for (int r = 0; r < TI; ++r) {
        const int i = i0 + r;
        const float siv = si_ws[b * NN + i];
        const f32x4* efr = (const f32x4*)(ef + (((size_t)b * NN + i) * NN) * 16);
        const int f0 = t * 4, f1 = (t + 256) * 4;
        const f32x4 u0 = __builtin_nontemporal_load(efr + f0 + 0);
        const f32x4 u1 = __builtin_nontemporal_load(efr + f0 + 1);
        const f32x4 u2 = __builtin_nontemporal_load(efr + f0 + 2);
        const f32x4 u3 = __builtin_nontemporal_load(efr + f0 + 3);
        const f32x4 v0 = __builtin_nontemporal_load(efr + f1 + 0);
        const f32x4 v1 = __builtin_nontemporal_load(efr + f1 + 1);
        const f32x4 v2 = __builtin_nontemporal_load(efr + f1 + 2);
        const f32x4 v3 = __builtin_nontemporal_load(efr + f1 + 3);
        const float s0 = dotv(u0, A0) + dotv(u1, A1) + dotv(u2, A2) + dotv(u3, A3);
        const float s1 = dotv(v0, A0) + dotv(v1, A1) + dotv(v2, A2) + dotv(v3, A3);
        e0[r] = (siv + sj_l[t] + s0) * SCALE;
        e1[r] = (siv + sj_l[t + 256] + s1) * SCALE;
        float m = fmaxf(e0[r], e1[r]);
#pragma unroll
        for (int mm = 32; mm >= 1; mm >>= 1) m = fmaxf(m, __shfl_xor(m, mm));
        if (lane == 0) redm[r][w] = m;
    }
    __syncthreads();

    // Phase B: exp + row sums; unnormalized alpha stored transposed
#pragma unroll
    for (int r = 0; r < TI; ++r) {
        const float mx = fmaxf(fmaxf(redm[r][0], redm[r][1]),
                               fmaxf(redm[r][2], redm[r][3]));
        const float a0 = __expf(e0[r] - mx);
        const float a1 = __expf(e1[r] - mx);
        alpha_t[t][r] = a0;
        alpha_t[t + 256][r] = a1;
        float s = a0 + a1;
#pragma unroll
        for (int mm = 32; mm >= 1; mm >>= 1) s += __shfl_xor(s, mm);
        if (lane == 0) reds[r][w] = s;
    }
    __syncthreads();

    // Phase C: h' = alpha @ h. thread -> 4 consecutive d, 1 of 8 j-groups
    const int dl = (t & 31) << 2;
    const int g = t >> 5;
    float acc[TI][4];
#pragma unroll
    for (int r = 0; r < TI; ++r)
#pragma unroll
        for (int c = 0; c < 4; ++c) acc[r][c] = 0.f;

    const float* hb = h_ws + (size_t)b * NN * D;
    for (int jj = 0; jj < 64; ++jj) {
        const int j = (g << 6) + jj;
        const float4 hv = *(const float4*)(hb + j * D + dl);
        const float4 al = *(const float4*)(&alpha_t[j][0]);
        const float ar[TI] = {al.x, al.y, al.z, al.w};
        const float hc[4] = {hv.x, hv.y, hv.z, hv.w};
#pragma unroll
        for (int r = 0; r < TI; ++r)
#pragma unroll
            for (int c = 0; c < 4; ++c) acc[r][c] += ar[r] * hc[c];
    }
#pragma unroll
    for (int r = 0; r < TI; ++r)
#pragma unroll
        for (int c = 0; c < 4; ++c) acc[r][c] += __shfl_xor(acc[r][c], 32);
    if ((t & 63) < 32) {
#pragma unroll
        for (int r = 0; r < TI; ++r)
            *(float4*)&part[w][r][dl] = make_float4(acc[r][0], acc[r][1], acc[r][2], acc[r][3]);
    }
    __syncthreads();

    // Phase D: LayerNorm. wave w handles row w; lane -> d, d+64
    {
        const int r = w;
        const float inv = 1.0f / (reds[r][0] + reds[r][1] + reds[r][2] + reds[r][3]);
        const int d0 = lane, d1 = lane + 64;
        const float v0 = (part[0][r][d0] + part[1][r][d0] + part[2][r][d0] + part[3][r][d0]) * inv;
        const float v1 = (part[0][r][d1] + part[1][r][d1] + part[2][r][d1] + part[3][r][d1]) * inv;
        float s = v0 + v1, q = v0 * v0 + v1 * v1;
#pragma unroll
        for (int mm = 32; mm >= 1; mm >>= 1) {
            s += __shfl_xor(s, mm);
            q += __shfl_xor(q, mm);
        }
        const float mu = s * (1.f / 128.f);
        const float var = q * (1.f / 128.f) - mu * mu;
        const float rs = rsqrtf(var + LN_EPS);
        const size_t ob = ((size_t)(b * NN + i0 + r)) * D;
        out[ob + d0] = (v0 - mu) * rs * gamma[d0] + beta[d0];
        out[ob + d1] = (v1 - mu) * rs * gamma[d1] + beta[d1];
    }
}

extern "C" void kernel_launch(void* const* d_in, const int* in_sizes, int n_in,
                              void* d_out, int out_size, void* d_ws, size_t ws_size,
                              hipStream_t stream) {
    const float* x     = (const float*)d_in[0];
    const float* ef    = (const float*)d_in[1];
    const float* W     = (const float*)d_in[2];
    const float* a_src = (const float*)d_in[3];
    const float* a_dst = (const float*)d_in[4];
    const float* a_e   = (const float*)d_in[5];
    const float* gamma = (const float*)d_in[6];
    const float* beta  = (const float*)d_in[7];
    float* out = (float*)d_out;

    float* h_ws  = (float*)d_ws;                       // 2 MiB
    float* si_ws = h_ws + (size_t)NB * NN * D;
    float* sj_ws = si_ws + NB * NN;

    k1_proj<<<NB * NN / K1R, 256, 0, stream>>>(x, W, a_src, a_dst, h_ws, si_ws, sj_ws);
    k2_attn<<<NB * (NN / TI), 256, 0, stream>>>(ef, a_e, gamma, beta,
                                                h_ws, si_ws, sj_ws, out);
}

// Round 3
// 61.197 us; speedup vs baseline: 1.1464x; 1.1464x over previous
//
#include <hip/hip_runtime.h>
#include <math.h>

#define NB 8
#define NN 512
#define D 128
#define TI 8          // query rows per k2 block
#define K1R 8         // rows per k1 block
#define LN_EPS 1e-5f
#define SCALE 0.08838834764831845f  // 1/sqrt(128)

#define KE_BLOCKS 2048
#define KE_NTH (KE_BLOCKS * 256)          // 524288 threads
#define TOT_F4 (NB * NN * NN * 4)         // 8388608 float4 in edge_feats

typedef float f32x4 __attribute__((ext_vector_type(4)));

__device__ __forceinline__ float dotv(f32x4 a, f32x4 b) {
    f32x4 m = a * b;
    return m.x + m.y + m.z + m.w;
}
__device__ __forceinline__ float dot4(float4 a, float4 b) {
    return a.x * b.x + a.y * b.y + a.z * b.z + a.w * b.w;
}

// ---------------- Kernel E: s_e[b,i,j] = edge_feats[b,i,j,:] . a_e ----------
// Pure streaming, fill-like shape: lane-contiguous float4 loads, 4-lane reduce.
__global__ __launch_bounds__(256) void ke_scores(
    const float* __restrict__ ef, const float* __restrict__ a_e,
    float* __restrict__ se_ws)
{
    const int g = blockIdx.x * 256 + threadIdx.x;
    const int c = g & 3;                       // which quarter of the 16-dim edge
    const f32x4 A = ((const f32x4*)a_e)[c];    // per-thread constant
    const f32x4* ef4 = (const f32x4*)ef;
#pragma unroll 4
    for (int k = 0; k < TOT_F4 / KE_NTH; ++k) {
        const size_t f = (size_t)k * KE_NTH + g;     // lane-contiguous
        const f32x4 v = ef4[f];
        float p = dotv(v, A);
        p += __shfl_xor(p, 1);
        p += __shfl_xor(p, 2);
        if (c == 0) se_ws[f >> 2] = p;               // 16 lanes/wave, 64B/wave
    }
}

// ---------------- Kernel 1: h = x @ W^T, s_i, s_j ---------------------------
// grid: 512 blocks (8 rows each), block: 256. W staged in LDS (swizzled).
__global__ __launch_bounds__(256) void k1_proj(
    const float* __restrict__ x, const float* __restrict__ W,
    const float* __restrict__ a_src, const float* __restrict__ a_dst,
    float* __restrict__ h_ws, float* __restrict__ si_ws, float* __restrict__ sj_ws)
{
    __shared__ __align__(16) float4 Wl[128][32];   // [o][q ^ (o&7)] swizzle
    __shared__ __align__(16) float4 xl[K1R][32];
    __shared__ float redk[K1R][2][2];

    const int t = threadIdx.x;
    const int row0 = blockIdx.x * K1R;

    const float4* Wg = (const float4*)W;
#pragma unroll
    for (int k = 0; k < 16; ++k) {
        const int f = t + 256 * k;          // 4096 float4 of W
        const int o = f >> 5, q = f & 31;
        Wl[o][q ^ (o & 7)] = Wg[f];
    }
    xl[t >> 5][t & 31] = ((const float4*)(x + (size_t)row0 * D))[t];  // 256 float4
    __syncthreads();

    const int o = t & 127;
    const int rb = (t >> 7) * (K1R / 2);    // rows 0-3 or 4-7
    float acc[K1R / 2] = {0.f, 0.f, 0.f, 0.f};
#pragma unroll
    for (int q = 0; q < 32; ++q) {
        const float4 wv = Wl[o][q ^ (o & 7)];
#pragma unroll
        for (int r = 0; r < K1R / 2; ++r) acc[r] += dot4(wv, xl[rb + r][q]);
    }
    const float as = a_src[o], ad = a_dst[o];
#pragma unroll
    for (int r = 0; r < K1R / 2; ++r) {
        h_ws[(size_t)(row0 + rb + r) * D + o] = acc[r];
        float vs = acc[r] * as, vd = acc[r] * ad;
#pragma unroll
        for (int m = 32; m >= 1; m >>= 1) {
            vs += __shfl_xor(vs, m);
            vd += __shfl_xor(vd, m);
        }
        if ((t & 63) == 0) {
            redk[rb + r][0][(t >> 6) & 1] = vs;
            redk[rb + r][1][(t >> 6) & 1] = vd;
        }
    }
    __syncthreads();
    if (t < K1R) si_ws[row0 + t] = redk[t][0][0] + redk[t][0][1];
    else if (t < 2 * K1R) {
        const int r = t - K1R;
        sj_ws[row0 + r] = redk[r][1][0] + redk[r][1][1];
    }
}

// ---------------- Kernel 2: softmax + PV + LayerNorm ------------------------
// grid: 8 * 64 = 512 blocks (TI=8 rows each), block: 256
__global__ __launch_bounds__(256) void k2_attn(
    const float* __restrict__ se_ws,
    const float* __restrict__ gamma, const float* __restrict__ beta,
    const float* __restrict__ h_ws, const float* __restrict__ si_ws,
    const float* __restrict__ sj_ws, float* __restrict__ out)
{
    __shared__ float sj_l[NN];                        // 2 KB
    __shared__ __align__(16) float alpha_t[NN][TI];   // 16 KB, [j][r]
    __shared__ __align__(16) float part[4][TI][D];    // 16 KB
    __shared__ float redm[TI][4];
    __shared__ float reds[TI][4];

    const int t = threadIdx.x;
    const int w = t >> 6;
    const int lane = t & 63;
    const int bid = blockIdx.x;
    const int b = bid >> 6;
    const int i0 = (bid & 63) << 3;

    sj_l[t] = sj_ws[b * NN + t];
    sj_l[t + 256] = sj_ws[b * NN + t + 256];
    __syncthreads();

    // Phase A: scores from precomputed s_e; thread owns j = t and j = t+256
    float e0[TI], e1[TI];
#pragma unroll
    for (int r = 0; r < TI; ++r) {
        const int i = i0 + r;
        const float siv = si_ws[b * NN + i];
        const float* ser = se_ws + ((size_t)b * NN + i) * NN;
        const float s0 = ser[t];
        const float s1 = ser[t + 256];
        e0[r] = (siv + sj_l[t] + s0) * SCALE;
        e1[r] = (siv + sj_l[t + 256] + s1) * SCALE;
        float m = fmaxf(e0[r], e1[r]);
#pragma unroll
        for (int mm = 32; mm >= 1; mm >>= 1) m = fmaxf(m, __shfl_xor(m, mm));
        if (lane == 0) redm[r][w] = m;
    }
    __syncthreads();

    // Phase B: exp + row sums; unnormalized alpha stored transposed
#pragma unroll
    for (int r = 0; r < TI; ++r) {
        const float mx = fmaxf(fmaxf(redm[r][0], redm[r][1]),
                               fmaxf(redm[r][2], redm[r][3]));
        const float a0 = __expf(e0[r] - mx);
        const float a1 = __expf(e1[r] - mx);
        alpha_t[t][r] = a0;
        alpha_t[t + 256][r] = a1;
        float s = a0 + a1;
#pragma unroll
        for (int mm = 32; mm >= 1; mm >>= 1) s += __shfl_xor(s, mm);
        if (lane == 0) reds[r][w] = s;
    }
    __syncthreads();

    // Phase C: h' = alpha @ h. thread -> 4 consecutive d, 1 of 8 j-groups
    const int dl = (t & 31) << 2;
    const int g = t >> 5;
    float acc[TI][4];
#pragma unroll
    for (int r = 0; r < TI; ++r)
#pragma unroll
        for (int c = 0; c < 4; ++c) acc[r][c] = 0.f;

    const float* hb = h_ws + (size_t)b * NN * D;
    for (int jj = 0; jj < 64; ++jj) {
        const int j = (g << 6) + jj;
        const float4 hv = *(const float4*)(hb + j * D + dl);
        const float4 al0 = *(const float4*)(&alpha_t[j][0]);
        const float4 al1 = *(const float4*)(&alpha_t[j][4]);
        const float ar[TI] = {al0.x, al0.y, al0.z, al0.w, al1.x, al1.y, al1.z, al1.w};
        const float hc[4] = {hv.x, hv.y, hv.z, hv.w};
#pragma unroll
        for (int r = 0; r < TI; ++r)
#pragma unroll
            for (int c = 0; c < 4; ++c) acc[r][c] += ar[r] * hc[c];
    }
#pragma unroll
    for (int r = 0; r < TI; ++r)
#pragma unroll
        for (int c = 0; c < 4; ++c) acc[r][c] += __shfl_xor(acc[r][c], 32);
    if ((t & 63) < 32) {
#pragma unroll
        for (int r = 0; r < TI; ++r)
            *(float4*)&part[w][r][dl] = make_float4(acc[r][0], acc[r][1], acc[r][2], acc[r][3]);
    }
    __syncthreads();

    // Phase D: LayerNorm. wave w handles rows 2w, 2w+1; lane -> d, d+64
#pragma unroll
    for (int rr = 0; rr < 2; ++rr) {
        const int r = w * 2 + rr;
        const float inv = 1.0f / (reds[r][0] + reds[r][1] + reds[r][2] + reds[r][3]);
        const int d0 = lane, d1 = lane + 64;
        const float v0 = (part[0][r][d0] + part[1][r][d0] + part[2][r][d0] + part[3][r][d0]) * inv;
        const float v1 = (part[0][r][d1] + part[1][r][d1] + part[2][r][d1] + part[3][r][d1]) * inv;
        float s = v0 + v1, q = v0 * v0 + v1 * v1;
#pragma unroll
        for (int mm = 32; mm >= 1; mm >>= 1) {
            s += __shfl_xor(s, mm);
            q += __shfl_xor(q, mm);
        }
        const float mu = s * (1.f / 128.f);
        const float var = q * (1.f / 128.f) - mu * mu;
        const float rs = rsqrtf(var + LN_EPS);
        const size_t ob = ((size_t)(b * NN + i0 + r)) * D;
        out[ob + d0] = (v0 - mu) * rs * gamma[d0] + beta[d0];
        out[ob + d1] = (v1 - mu) * rs * gamma[d1] + beta[d1];
    }
}

extern "C" void kernel_launch(void* const* d_in, const int* in_sizes, int n_in,
                              void* d_out, int out_size, void* d_ws, size_t ws_size,
                              hipStream_t stream) {
    const float* x     = (const float*)d_in[0];
    const float* ef    = (const float*)d_in[1];
    const float* W     = (const float*)d_in[2];
    const float* a_src = (const float*)d_in[3];
    const float* a_dst = (const float*)d_in[4];
    const float* a_e   = (const float*)d_in[5];
    const float* gamma = (const float*)d_in[6];
    const float* beta  = (const float*)d_in[7];
    float* out = (float*)d_out;

    float* h_ws  = (float*)d_ws;                       // 2 MiB
    float* si_ws = h_ws + (size_t)NB * NN * D;         // 16 KiB
    float* sj_ws = si_ws + NB * NN;                    // 16 KiB
    float* se_ws = (float*)((char*)d_ws + (4u << 20)); // 8 MiB @ +4 MiB

    ke_scores<<<KE_BLOCKS, 256, 0, stream>>>(ef, a_e, se_ws);
    k1_proj<<<NB * NN / K1R, 256, 0, stream>>>(x, W, a_src, a_dst, h_ws, si_ws, sj_ws);
    k2_attn<<<NB * (NN / TI), 256, 0, stream>>>(se_ws, gamma, beta,
                                                h_ws, si_ws, sj_ws, out);
}